// Round 4
// baseline (289.415 us; speedup 1.0000x reference)
//
#include <hip/hip_runtime.h>
#include <stdint.h>

#define T_LEN 1024
#define NSTATE 32

__device__ __forceinline__ float max3f(float a, float b, float c) {
    return fmaxf(fmaxf(a, b), c);   // v_max3_f32
}

__launch_bounds__(64)
__global__ void viterbi_kernel(const float* __restrict__ logits,
                               const float* __restrict__ trans,
                               const int* __restrict__ seqlen,
                               int* __restrict__ out)
{
    const int lane = threadIdx.x;   // 0..63
    const int j    = lane & 31;     // output column (lanes j and j+32 duplicate)

    __shared__ uint8_t bp[T_LEN * NSTATE];      // backptrs, t=1..L-1
    __shared__ uint8_t Farr[32 * 32];           // chunk functions
    __shared__ uint8_t earr[32];                // chunk entry tags
    __shared__ __align__(16) int pred[T_LEN];   // output row

    int L = seqlen[blockIdx.x];
    if (L < 0) L = 0;
    if (L > 1023) L = 1023;

    // full transition column j in registers (all 32 source states)
    float tr[NSTATE];
#pragma unroll
    for (int k = 0; k < NSTATE; ++k)
        tr[k] = trans[k * NSTATE + j];

    const float* lg = logits + (size_t)blockIdx.x * T_LEN * NSTATE;

    // state[j] lives in lanes j and j+32 (duplicated)
    float ns = lg[j];

    // one forward step: consumes logit value lgt for time t.
    // Broadcast state via v_readlane (VALU pipe) -> zero DS on the chain.
    auto step = [&](int t, float lgt) {
        int nsb = __float_as_int(ns);
        float v[NSTATE];
#pragma unroll
        for (int k = 0; k < NSTATE; ++k) {
            int sk = __builtin_amdgcn_readlane(nsb, k);   // constant lane idx
            v[k] = __int_as_float(sk) + tr[k];
        }

        // order-preserving max3 tree over 32 candidates (17 ops, depth 4)
        float g0 = max3f(v[0],  v[1],  v[2]);
        float g1 = max3f(v[3],  v[4],  v[5]);
        float g2 = max3f(v[6],  v[7],  v[8]);
        float g3 = max3f(v[9],  v[10], v[11]);
        float g4 = max3f(v[12], v[13], v[14]);
        float g5 = max3f(v[15], v[16], v[17]);
        float g6 = max3f(v[18], v[19], v[20]);
        float g7 = max3f(v[21], v[22], v[23]);
        float g8 = max3f(v[24], v[25], v[26]);
        float g9 = max3f(v[27], v[28], v[29]);
        float g10 = fmaxf(v[30], v[31]);
        float h0 = max3f(g0, g1, g2);
        float h1 = max3f(g3, g4, g5);
        float h2 = max3f(g6, g7, g8);
        float h3 = fmaxf(g9, g10);
        float gm = fmaxf(max3f(h0, h1, h2), h3);

        ns = gm + lgt;   // same add order as reference

        // exact first-occurrence argmax: two 16-deep cndmask cascades + min
        int ia = 64, ib = 64;
#pragma unroll
        for (int k = 15; k >= 0; --k) ia = (v[k] == gm) ? k : ia;
#pragma unroll
        for (int k = 31; k >= 16; --k) ib = (v[k] == gm) ? k : ib;
        int idx = min(ia, ib);

        bp[t * NSTATE + j] = (uint8_t)idx;   // only DS op in the loop
    };

    // ---------------- forward (single wave: no barriers) ----------------
    if (L >= 2) {
        float pre[8];
#pragma unroll
        for (int d = 0; d < 8; ++d) {
            int tp = 1 + d; if (tp > 1023) tp = 1023;
            pre[d] = lg[tp * NSTATE + j];
        }
        int t = 1;
        for (; t + 8 <= L; t += 8) {
#pragma unroll
            for (int u = 0; u < 8; ++u) {
                step(t + u, pre[u]);
                int tp = t + 8 + u; if (tp > 1023) tp = 1023;
                pre[u] = lg[tp * NSTATE + j];
            }
        }
        for (int k = 0; t < L; ++t, ++k) step(t, pre[k]);
    }

    // ---------------- last_tag = argmax(final state) ----------------
    float m = ns;
#pragma unroll
    for (int d = 1; d < 32; d <<= 1) m = fmaxf(m, __shfl_xor(m, d));
    int ii = (ns == m) ? j : 64;
#pragma unroll
    for (int d = 1; d < 32; d <<= 1) ii = min(ii, __shfl_xor(ii, d));
    const int ft = ii;   // last tag (identical in all lanes)

    __syncthreads();   // bp visible for backtrace

    if (L >= 2) {
        // ---- phase 1: chunk functions, all 32 start states ----
        const int c = lane & 31;
        const int j0base = (lane >> 5) * 16;
        int tags[16];
#pragma unroll
        for (int k = 0; k < 16; ++k) tags[k] = j0base + k;
        const int thi = c * 32 + 31;
        for (int s = 0; s < 32; ++s) {
            int t = thi - s;
            bool valid = (t >= 1) && (t <= L - 1);
            int tc = t < 1 ? 1 : (t > L - 1 ? L - 1 : t);
            int base = tc * NSTATE;
#pragma unroll
            for (int k = 0; k < 16; ++k) {
                int nt = bp[base + tags[k]];
                tags[k] = valid ? nt : tags[k];
            }
        }
#pragma unroll
        for (int k = 0; k < 16; ++k)
            Farr[c * 32 + j0base + k] = (uint8_t)tags[k];
        __syncthreads();

        // ---- phase 2: compose chunk entries (serial, 32 steps) ----
        if (lane == 0) {
            int e = ft;
            for (int c2 = 31; c2 >= 0; --c2) {
                earr[c2] = (uint8_t)e;
                e = Farr[c2 * 32 + e];
            }
        }
        __syncthreads();

        // ---- phase 3: re-walk chunks in parallel, emit pred ----
        if (lane < 32) {
            int tag = earr[lane];
            const int thi3 = lane * 32 + 31;
            for (int s = 0; s < 32; ++s) {
                int t = thi3 - s;
                pred[t] = (t < L) ? tag : 0;
                bool valid = (t >= 1) && (t <= L - 1);
                int tc = t < 1 ? 1 : (t > L - 1 ? L - 1 : t);
                int nt = bp[tc * NSTATE + tag];
                tag = valid ? nt : tag;
            }
        }
        __syncthreads();
    } else {
        // L == 0 or 1
#pragma unroll
        for (int r = 0; r < 16; ++r) pred[lane * 16 + r] = 0;
        __syncthreads();
        if (lane == 0 && L == 1) pred[0] = ft;
        __syncthreads();
    }

    // ---------------- coalesced store ----------------
    int4* out4 = reinterpret_cast<int4*>(out + (size_t)blockIdx.x * T_LEN);
    const int4* p4 = reinterpret_cast<const int4*>(pred);
#pragma unroll
    for (int r = 0; r < 4; ++r)
        out4[r * 64 + lane] = p4[r * 64 + lane];
}

extern "C" void kernel_launch(void* const* d_in, const int* in_sizes, int n_in,
                              void* d_out, int out_size, void* d_ws, size_t ws_size,
                              hipStream_t stream) {
    const float* logits = (const float*)d_in[0];
    const float* trans  = (const float*)d_in[1];
    const int*   slen   = (const int*)d_in[2];
    int*         out    = (int*)d_out;
    const int B = in_sizes[2];   // 1024

    viterbi_kernel<<<dim3(B), dim3(64), 0, stream>>>(logits, trans, slen, out);
}